// Round 5
// baseline (312.813 us; speedup 1.0000x reference)
//
#include <hip/hip_runtime.h>

static constexpr float kThresh = 0.01f;
static constexpr int TPB     = 256;
static constexpr int PBLOCKS = 2048;   // stage-1 grid: 8 blocks/CU -> 32 waves/CU (round-4's 1024 halved occupancy and throughput)
static constexpr int FBLOCKS = 2048;   // fallback stage-1 grid

// Monotone float <-> uint key: k(a) < k(b)  <=>  a < b  (for non-NaN floats)
__device__ __forceinline__ unsigned fkey(float f) {
    unsigned u = __float_as_uint(f);
    return (u & 0x80000000u) ? ~u : (u | 0x80000000u);
}
__device__ __forceinline__ float unkey(unsigned k) {
    unsigned u = (k & 0x80000000u) ? (k & 0x7fffffffu) : ~k;
    return __uint_as_float(u);
}

__device__ __forceinline__ void acc_one(float x, unsigned& smin, unsigned& smax,
                                        unsigned& lmin, unsigned& lmax) {
    unsigned k = fkey(x);
    if (fabsf(x) > kThresh) {
        lmin = min(lmin, k);
        lmax = max(lmax, k);
    } else {
        smin = min(smin, k);
        smax = max(smax, k);
    }
}

__device__ __forceinline__ void acc4(float4 v, unsigned& smin, unsigned& smax,
                                     unsigned& lmin, unsigned& lmax) {
    acc_one(v.x, smin, smax, lmin, lmax);
    acc_one(v.y, smin, smax, lmin, lmax);
    acc_one(v.z, smin, smax, lmin, lmax);
    acc_one(v.w, smin, smax, lmin, lmax);
}

__device__ __forceinline__ void wave_reduce4(unsigned& smin, unsigned& smax,
                                             unsigned& lmin, unsigned& lmax) {
    #pragma unroll
    for (int off = 32; off > 0; off >>= 1) {
        smin = min(smin, (unsigned)__shfl_down((int)smin, off));
        smax = max(smax, (unsigned)__shfl_down((int)smax, off));
        lmin = min(lmin, (unsigned)__shfl_down((int)lmin, off));
        lmax = max(lmax, (unsigned)__shfl_down((int)lmax, off));
    }
}

__device__ __forceinline__ float deq1(float x, float smin, float ssc, float sis, bool sv,
                                      float lmin, float lsc, float lis, bool lv) {
    bool large = fabsf(x) > kThresh;
    float bmin = large ? lmin : smin;
    float sc   = large ? lsc : ssc;
    float is   = large ? lis : sis;
    bool  v    = large ? lv : sv;
    float q = rintf((x - bmin) * sc);          // round((x-bmin)/denom*levels), half-to-even
    float d = fmaf(q, is, bmin);               // q/levels*denom + bmin
    return v ? d : x;
}

// ---------------------------------------------------------------------------
// Stage 1: block-local min/max per bin, then 4 device-scope atomicMin into
// ws[0..3]. Max keys are stored COMPLEMENTED so min/max both reduce via
// atomicMin and a single 0xFF memset initializes all four identities.
//   ws[0] = smin_key        ws[1] = lmin_key
//   ws[2] = ~smax_key       ws[3] = ~lmax_key
// ---------------------------------------------------------------------------
__global__ __launch_bounds__(TPB) void kv_partial_atomic(const float* __restrict__ in, int n,
                                                         unsigned* __restrict__ ws) {
    unsigned smin = 0xFFFFFFFFu, smax = 0u, lmin = 0xFFFFFFFFu, lmax = 0u;
    const int n4 = n >> 2;
    const float4* __restrict__ in4 = (const float4*)in;
    const int stride = gridDim.x * TPB;
    int i = blockIdx.x * TPB + threadIdx.x;
    for (; i + 3 * stride < n4; i += 4 * stride) {
        float4 a = in4[i];
        float4 b = in4[i + stride];
        float4 c = in4[i + 2 * stride];
        float4 d = in4[i + 3 * stride];
        acc4(a, smin, smax, lmin, lmax);
        acc4(b, smin, smax, lmin, lmax);
        acc4(c, smin, smax, lmin, lmax);
        acc4(d, smin, smax, lmin, lmax);
    }
    for (; i < n4; i += stride) acc4(in4[i], smin, smax, lmin, lmax);
    for (int j = (n4 << 2) + blockIdx.x * TPB + threadIdx.x; j < n; j += stride)
        acc_one(in[j], smin, smax, lmin, lmax);

    wave_reduce4(smin, smax, lmin, lmax);

    __shared__ unsigned ls[4][4];
    const int wave = threadIdx.x >> 6;
    if ((threadIdx.x & 63) == 0) {
        ls[wave][0] = smin; ls[wave][1] = smax; ls[wave][2] = lmin; ls[wave][3] = lmax;
    }
    __syncthreads();
    if (threadIdx.x == 0) {
        unsigned a = ls[0][0], b = ls[0][1], c = ls[0][2], d = ls[0][3];
        #pragma unroll
        for (int w = 1; w < 4; ++w) {
            a = min(a, ls[w][0]); b = max(b, ls[w][1]);
            c = min(c, ls[w][2]); d = max(d, ls[w][3]);
        }
        atomicMin(&ws[0], a);
        atomicMin(&ws[1], c);
        atomicMin(&ws[2], ~b);   // complemented max
        atomicMin(&ws[3], ~d);   // complemented max
    }
}

// ---------------------------------------------------------------------------
// Stage 2: one-shot dequant, 2 float4 per thread (dual loads in flight).
// ws reads are wave-uniform scalar loads; no LDS, no __syncthreads.
// (Measured ~30 us incl. gap in round 4 — near the ~25 us write-bound floor.)
// ---------------------------------------------------------------------------
__global__ __launch_bounds__(TPB) void kv_dequant_os(const float* __restrict__ in,
                                                     float* __restrict__ out, int n,
                                                     const unsigned* __restrict__ ws) {
    const unsigned sk0 = ws[0], lk0 = ws[1];
    const unsigned sk1 = ~ws[2], lk1 = ~ws[3];
    const bool sv = sk0 < sk1;     // valid = has_any && (bmax != bmin)
    const bool lv = lk0 < lk1;
    const float smin = unkey(sk0);
    const float sden = sv ? (unkey(sk1) - smin) : 1.0f;
    const float lmin = unkey(lk0);
    const float lden = lv ? (unkey(lk1) - lmin) : 1.0f;
    const float ssc = 15.0f / sden,  sis = sden / 15.0f;
    const float lsc = 255.0f / lden, lis = lden / 255.0f;

    const int n4 = n >> 2;
    const int T  = gridDim.x * TPB;          // total threads; covers n4 in 2 shots
    const int k  = blockIdx.x * TPB + threadIdx.x;
    const float4* __restrict__ in4 = (const float4*)in;
    float4* __restrict__ out4 = (float4*)out;

    if (k < n4) {
        float4 a = in4[k];
        float4 r;
        r.x = deq1(a.x, smin, ssc, sis, sv, lmin, lsc, lis, lv);
        r.y = deq1(a.y, smin, ssc, sis, sv, lmin, lsc, lis, lv);
        r.z = deq1(a.z, smin, ssc, sis, sv, lmin, lsc, lis, lv);
        r.w = deq1(a.w, smin, ssc, sis, sv, lmin, lsc, lis, lv);
        out4[k] = r;
    }
    const int k2 = k + T;
    if (k2 < n4) {
        float4 a = in4[k2];
        float4 r;
        r.x = deq1(a.x, smin, ssc, sis, sv, lmin, lsc, lis, lv);
        r.y = deq1(a.y, smin, ssc, sis, sv, lmin, lsc, lis, lv);
        r.z = deq1(a.z, smin, ssc, sis, sv, lmin, lsc, lis, lv);
        r.w = deq1(a.w, smin, ssc, sis, sv, lmin, lsc, lis, lv);
        out4[k2] = r;
    }
    const int tail = n - (n4 << 2);
    if (k < tail) {
        int j = (n4 << 2) + k;
        out[j] = deq1(in[j], smin, ssc, sis, sv, lmin, lsc, lis, lv);
    }
}

// ---------------------------------------------------------------------------
// Fallback path (no-workspace case): proven 3-kernel structure.
// ---------------------------------------------------------------------------
__global__ __launch_bounds__(TPB) void kv_partial(const float* __restrict__ in, int n,
                                                  unsigned* __restrict__ partials) {
    unsigned smin = 0xFFFFFFFFu, smax = 0u, lmin = 0xFFFFFFFFu, lmax = 0u;
    const int n4 = n >> 2;
    const float4* __restrict__ in4 = (const float4*)in;
    const int stride = gridDim.x * TPB;
    int i = blockIdx.x * TPB + threadIdx.x;
    for (; i + 3 * stride < n4; i += 4 * stride) {
        float4 a = in4[i];
        float4 b = in4[i + stride];
        float4 c = in4[i + 2 * stride];
        float4 d = in4[i + 3 * stride];
        acc4(a, smin, smax, lmin, lmax);
        acc4(b, smin, smax, lmin, lmax);
        acc4(c, smin, smax, lmin, lmax);
        acc4(d, smin, smax, lmin, lmax);
    }
    for (; i < n4; i += stride) acc4(in4[i], smin, smax, lmin, lmax);
    for (int j = (n4 << 2) + blockIdx.x * TPB + threadIdx.x; j < n; j += stride)
        acc_one(in[j], smin, smax, lmin, lmax);

    wave_reduce4(smin, smax, lmin, lmax);

    __shared__ unsigned ls[4][4];
    const int wave = threadIdx.x >> 6;
    if ((threadIdx.x & 63) == 0) {
        ls[wave][0] = smin; ls[wave][1] = smax; ls[wave][2] = lmin; ls[wave][3] = lmax;
    }
    __syncthreads();
    if (threadIdx.x == 0) {
        unsigned a = ls[0][0], b = ls[0][1], c = ls[0][2], d = ls[0][3];
        #pragma unroll
        for (int w = 1; w < 4; ++w) {
            a = min(a, ls[w][0]); b = max(b, ls[w][1]);
            c = min(c, ls[w][2]); d = max(d, ls[w][3]);
        }
        partials[blockIdx.x * 4 + 0] = a;
        partials[blockIdx.x * 4 + 1] = b;
        partials[blockIdx.x * 4 + 2] = c;
        partials[blockIdx.x * 4 + 3] = d;
    }
}

__global__ __launch_bounds__(TPB) void kv_final(const unsigned* __restrict__ partials,
                                                unsigned* __restrict__ ws) {
    unsigned smin = 0xFFFFFFFFu, smax = 0u, lmin = 0xFFFFFFFFu, lmax = 0u;
    for (int i = threadIdx.x; i < FBLOCKS; i += TPB) {
        smin = min(smin, partials[4 * i + 0]);
        smax = max(smax, partials[4 * i + 1]);
        lmin = min(lmin, partials[4 * i + 2]);
        lmax = max(lmax, partials[4 * i + 3]);
    }
    wave_reduce4(smin, smax, lmin, lmax);

    __shared__ unsigned ls[4][4];
    const int wave = threadIdx.x >> 6;
    if ((threadIdx.x & 63) == 0) {
        ls[wave][0] = smin; ls[wave][1] = smax; ls[wave][2] = lmin; ls[wave][3] = lmax;
    }
    __syncthreads();
    if (threadIdx.x == 0) {
        unsigned a = ls[0][0], b = ls[0][1], c = ls[0][2], d = ls[0][3];
        #pragma unroll
        for (int w = 1; w < 4; ++w) {
            a = min(a, ls[w][0]); b = max(b, ls[w][1]);
            c = min(c, ls[w][2]); d = max(d, ls[w][3]);
        }
        // same layout as the atomic path: [smin, lmin, ~smax, ~lmax]
        ws[0] = a; ws[1] = c; ws[2] = ~b; ws[3] = ~d;
    }
}

extern "C" void kernel_launch(void* const* d_in, const int* in_sizes, int n_in,
                              void* d_out, int out_size, void* d_ws, size_t ws_size,
                              hipStream_t stream) {
    const float* in = (const float*)d_in[0];
    float* out = (float*)d_out;
    unsigned* ws = (unsigned*)d_ws;
    const int n = in_sizes[0];

    const int n4 = n >> 2;
    int dblocks = (n4 + 2 * TPB - 1) / (2 * TPB);   // 2 float4 per thread
    if (dblocks < 1) dblocks = 1;

    if (ws_size >= 4 * sizeof(unsigned)) {
        // 2-kernel path: single memset initializes all four atomicMin identities.
        hipMemsetAsync(ws, 0xFF, 4 * sizeof(unsigned), stream);
        kv_partial_atomic<<<PBLOCKS, TPB, 0, stream>>>(in, n, ws);
        kv_dequant_os<<<dblocks, TPB, 0, stream>>>(in, out, n, ws);
    } else {
        // 3-kernel fallback: stage partials in d_out (read before dequant writes).
        unsigned* pt = (unsigned*)d_out;
        unsigned* w4 = (unsigned*)d_ws;   // still need 16 B; ws_size<16 shouldn't happen
        kv_partial<<<FBLOCKS, TPB, 0, stream>>>(in, n, pt);
        kv_final<<<1, TPB, 0, stream>>>(pt, w4);
        kv_dequant_os<<<dblocks, TPB, 0, stream>>>(in, out, n, w4);
    }
}

// Round 6
// 244.875 us; speedup vs baseline: 1.2774x; 1.2774x over previous
//
#include <hip/hip_runtime.h>

static constexpr float kThresh = 0.01f;
static constexpr int RBLOCKS = 2048;   // stage-1 grid; ONLY change vs round-0 (was 1024).
                                       // Depth-1 grid-stride loop kept: compiler software-
                                       // pipelines it (deep manual unrolls measured worse).
                                       // Partials-array finish kept: contended atomicMin
                                       // measured ~38 ns/block serialized tail (r4/r5).

// Monotone float <-> uint key: k(a) < k(b)  <=>  a < b  (for non-NaN floats)
__device__ __forceinline__ unsigned fkey(float f) {
    unsigned u = __float_as_uint(f);
    return (u & 0x80000000u) ? ~u : (u | 0x80000000u);
}
__device__ __forceinline__ float unkey(unsigned k) {
    unsigned u = (k & 0x80000000u) ? (k & 0x7fffffffu) : ~k;
    return __uint_as_float(u);
}

__device__ __forceinline__ void acc_one(float x, unsigned& smin, unsigned& smax,
                                        unsigned& lmin, unsigned& lmax) {
    unsigned k = fkey(x);
    if (fabsf(x) > kThresh) {
        lmin = min(lmin, k);
        lmax = max(lmax, k);
    } else {
        smin = min(smin, k);
        smax = max(smax, k);
    }
}

__device__ __forceinline__ void wave_reduce4(unsigned& smin, unsigned& smax,
                                             unsigned& lmin, unsigned& lmax) {
    #pragma unroll
    for (int off = 32; off > 0; off >>= 1) {
        smin = min(smin, (unsigned)__shfl_down((int)smin, off));
        smax = max(smax, (unsigned)__shfl_down((int)smax, off));
        lmin = min(lmin, (unsigned)__shfl_down((int)lmin, off));
        lmax = max(lmax, (unsigned)__shfl_down((int)lmax, off));
    }
}

// Stage 1: per-block min/max partials, NO global atomics.
// partials[blockIdx*4 + {0,1,2,3}] = {smin,smax,lmin,lmax} keys.
__global__ __launch_bounds__(256) void kv_partial(const float* __restrict__ in, int n,
                                                  unsigned* __restrict__ partials) {
    unsigned smin = 0xFFFFFFFFu, smax = 0u, lmin = 0xFFFFFFFFu, lmax = 0u;
    const int n4 = n >> 2;
    const float4* __restrict__ in4 = (const float4*)in;
    const int stride = gridDim.x * blockDim.x;
    for (int i = blockIdx.x * blockDim.x + threadIdx.x; i < n4; i += stride) {
        float4 v = in4[i];
        acc_one(v.x, smin, smax, lmin, lmax);
        acc_one(v.y, smin, smax, lmin, lmax);
        acc_one(v.z, smin, smax, lmin, lmax);
        acc_one(v.w, smin, smax, lmin, lmax);
    }
    for (int i = (n4 << 2) + blockIdx.x * blockDim.x + threadIdx.x; i < n; i += stride) {
        acc_one(in[i], smin, smax, lmin, lmax);
    }

    wave_reduce4(smin, smax, lmin, lmax);

    __shared__ unsigned ls[4][4];
    const int wave = threadIdx.x >> 6;
    if ((threadIdx.x & 63) == 0) {
        ls[wave][0] = smin; ls[wave][1] = smax; ls[wave][2] = lmin; ls[wave][3] = lmax;
    }
    __syncthreads();
    if (threadIdx.x == 0) {
        unsigned a = ls[0][0], b = ls[0][1], c = ls[0][2], d = ls[0][3];
        #pragma unroll
        for (int w = 1; w < 4; ++w) {
            a = min(a, ls[w][0]); b = max(b, ls[w][1]);
            c = min(c, ls[w][2]); d = max(d, ls[w][3]);
        }
        partials[blockIdx.x * 4 + 0] = a;
        partials[blockIdx.x * 4 + 1] = b;
        partials[blockIdx.x * 4 + 2] = c;
        partials[blockIdx.x * 4 + 3] = d;
    }
}

// Stage 2: one block folds RBLOCKS partial sets into ws[0..3].
__global__ __launch_bounds__(256) void kv_final(const unsigned* __restrict__ partials,
                                                unsigned* __restrict__ ws) {
    unsigned smin = 0xFFFFFFFFu, smax = 0u, lmin = 0xFFFFFFFFu, lmax = 0u;
    for (int i = threadIdx.x; i < RBLOCKS; i += 256) {
        smin = min(smin, partials[4 * i + 0]);
        smax = max(smax, partials[4 * i + 1]);
        lmin = min(lmin, partials[4 * i + 2]);
        lmax = max(lmax, partials[4 * i + 3]);
    }
    wave_reduce4(smin, smax, lmin, lmax);

    __shared__ unsigned ls[4][4];
    const int wave = threadIdx.x >> 6;
    if ((threadIdx.x & 63) == 0) {
        ls[wave][0] = smin; ls[wave][1] = smax; ls[wave][2] = lmin; ls[wave][3] = lmax;
    }
    __syncthreads();
    if (threadIdx.x == 0) {
        unsigned a = ls[0][0], b = ls[0][1], c = ls[0][2], d = ls[0][3];
        #pragma unroll
        for (int w = 1; w < 4; ++w) {
            a = min(a, ls[w][0]); b = max(b, ls[w][1]);
            c = min(c, ls[w][2]); d = max(d, ls[w][3]);
        }
        ws[0] = a; ws[1] = b; ws[2] = c; ws[3] = d;
    }
}

__device__ __forceinline__ float deq1(float x, float smin, float ssc, float sis, bool sv,
                                      float lmin, float lsc, float lis, bool lv) {
    bool large = fabsf(x) > kThresh;
    float bmin = large ? lmin : smin;
    float sc   = large ? lsc : ssc;
    float is   = large ? lis : sis;
    bool  v    = large ? lv : sv;
    float q = rintf((x - bmin) * sc);         // round((x-bmin)/denom*levels), half-to-even
    float d = fmaf(q, is, bmin);              // q/levels*denom + bmin
    return v ? d : x;
}

__global__ __launch_bounds__(256) void kv_dequant(const float* __restrict__ in,
                                                  float* __restrict__ out, int n,
                                                  const unsigned* __restrict__ ws) {
    const unsigned sk0 = ws[0], sk1 = ws[1], lk0 = ws[2], lk1 = ws[3];
    const bool sv = sk0 < sk1;     // valid = has_any && (bmax != bmin)
    const bool lv = lk0 < lk1;
    const float smin = unkey(sk0);
    const float sden = sv ? (unkey(sk1) - smin) : 1.0f;
    const float lmin = unkey(lk0);
    const float lden = lv ? (unkey(lk1) - lmin) : 1.0f;
    const float ssc = 15.0f / sden,  sis = sden / 15.0f;
    const float lsc = 255.0f / lden, lis = lden / 255.0f;

    const int n4 = n >> 2;
    const int i = blockIdx.x * blockDim.x + threadIdx.x;
    const float4* __restrict__ in4 = (const float4*)in;
    float4* __restrict__ out4 = (float4*)out;
    if (i < n4) {
        float4 v = in4[i];
        float4 r;
        r.x = deq1(v.x, smin, ssc, sis, sv, lmin, lsc, lis, lv);
        r.y = deq1(v.y, smin, ssc, sis, sv, lmin, lsc, lis, lv);
        r.z = deq1(v.z, smin, ssc, sis, sv, lmin, lsc, lis, lv);
        r.w = deq1(v.w, smin, ssc, sis, sv, lmin, lsc, lis, lv);
        out4[i] = r;
    }
    const int tail = n - (n4 << 2);
    if (i < tail) {
        int j = (n4 << 2) + i;
        out[j] = deq1(in[j], smin, ssc, sis, sv, lmin, lsc, lis, lv);
    }
}

extern "C" void kernel_launch(void* const* d_in, const int* in_sizes, int n_in,
                              void* d_out, int out_size, void* d_ws, size_t ws_size,
                              hipStream_t stream) {
    const float* in = (const float*)d_in[0];
    float* out = (float*)d_out;
    unsigned* ws = (unsigned*)d_ws;
    const int n = in_sizes[0];

    // Stage partials in d_out (32 KB at the front) — dequant overwrites all of
    // d_out afterwards, and stream ordering serializes the three kernels.
    unsigned* partials = (unsigned*)d_out;

    kv_partial<<<RBLOCKS, 256, 0, stream>>>(in, n, partials);
    kv_final<<<1, 256, 0, stream>>>(partials, ws);

    const int n4 = n >> 2;
    int dblocks = (n4 + 255) / 256;
    if (dblocks < 1) dblocks = 1;
    kv_dequant<<<dblocks, 256, 0, stream>>>(in, out, n, ws);
}